// Round 19
// baseline (109.321 us; speedup 1.0000x reference)
//
#include <hip/hip_runtime.h>
#include <hip/hip_bf16.h>

// RNN cell: out[B,N] = tanh( concat(x,hidden)[B,K] @ W^T[K,N] + b[N] )
// M=16384, N=1024, K=2048, fp32 in/out.
// Pass 1: fp32->bf16 cvt+concat into ws.
// Pass 2 (r19 = r16 with 32x32x16 MFMA): 256x256 whole-tile GEMM, 1024
//   threads = 16 waves (4M x 4N), 64x64 out/wave as 2x2 frags of 32x32.
//   Occupancy-ILP matrix closed: 16w is the win (73.5 vs 91/86), reg wall
//   blocks prefetch at 16w. Zero-reg lever left: MFMA shape. 32x32x16 =
//   2x FLOP/instr at same frag bytes -> half the lgkm gates + 32-cyc pipe
//   occupancy per MFMA (better cross-wave hiding) + faster pipe (m06:
//   2382 vs 2075 TF). acc stays 64 regs (2x2 x f32x16).

typedef __bf16 bf16_t;
typedef __bf16 bf16x8 __attribute__((ext_vector_type(8)));
typedef float  f32x16 __attribute__((ext_vector_type(16)));

#define M_GLOBAL 16384
#define N_GLOBAL 1024
#define K_GLOBAL 2048
#define IN_STRIDE 1024
#define NT 32

__device__ __forceinline__ float fast_tanh(float v) {
    float e = __expf(2.0f * v);
    return 1.0f - 2.0f * __builtin_amdgcn_rcpf(e + 1.0f);
}

// ---------------------------------------------------------------------------
// Pass 1: cvt + concat (~25 us measured; near BW floor).
// ---------------------------------------------------------------------------
#define XH_UNITS ((long long)M_GLOBAL * K_GLOBAL / 8)
#define W_UNITS  ((long long)N_GLOBAL * K_GLOBAL / 8)

__global__ __launch_bounds__(256)
void cvt_pass(const float* __restrict__ x, const float* __restrict__ h,
              const float* __restrict__ W,
              bf16_t* __restrict__ XHb, bf16_t* __restrict__ Wb)
{
    const long long total = XH_UNITS + W_UNITS;
    for (long long u = (long long)blockIdx.x * 256 + threadIdx.x; u < total;
         u += (long long)gridDim.x * 256) {
        const float* src;
        bf16_t* dst;
        if (u < XH_UNITS) {
            const long long e = u * 8;
            const int row = (int)(e >> 11);
            const int col = (int)(e & 2047);
            src = (col < 1024) ? (x + (long long)row * IN_STRIDE + col)
                               : (h + (long long)row * IN_STRIDE + (col - 1024));
            dst = XHb + e;
        } else {
            const long long e = (u - XH_UNITS) * 8;
            src = W + e;
            dst = Wb + e;
        }
        const float4 v0 = *(const float4*)src;
        const float4 v1 = *(const float4*)(src + 4);
        bf16x8 o;
        o[0] = (bf16_t)v0.x; o[1] = (bf16_t)v0.y;
        o[2] = (bf16_t)v0.z; o[3] = (bf16_t)v0.w;
        o[4] = (bf16_t)v1.x; o[5] = (bf16_t)v1.y;
        o[6] = (bf16_t)v1.z; o[7] = (bf16_t)v1.w;
        *(bf16x8*)dst = o;
    }
}

// ---------------------------------------------------------------------------
// Pass 2: 256x256 whole-tile GEMM, 16 waves of 64x64 (2x2 frags of 32x32).
// LDS: 2 dbuf x {A0,A1,B0,B1} 128x64 halves = 128 KB (1 block/CU).
// Swizzle (0 conflicts r7-r18): slot s of row r holds k-slot s^(r&7);
// applied on global SOURCE (gload_lds writes linearly, rule 21) + ds_read.
// 32x32x16 operand layout: lane reads row/col = lane&31, 8 contiguous k at
// (lane>>5)*8 within the K=16 step -> k-slot q = ks*2 + (lane>>5).
// Per 8 consecutive lanes: rows 0..7, slots q^0..q^7 all distinct ->
// conflict-free under the swizzle.
// Race audit (r13/r16): stage(t+1) at top of t; VM0 at end drains own
// loads; barrier after VM0 -> tile t+1 resident before any read. WAR: the
// staged buffer was last read in tile t-1, closed by the t-1 barrier.
// ---------------------------------------------------------------------------
__device__ __forceinline__ void gload_lds16(const bf16_t* g, bf16_t* l) {
    __builtin_amdgcn_global_load_lds(
        (const __attribute__((address_space(1))) void*)g,
        (__attribute__((address_space(3))) void*)l, 16, 0, 0);
}

__global__ __launch_bounds__(1024)
void gemm_w32(const bf16_t* __restrict__ XHb, const bf16_t* __restrict__ Wb,
              const float* __restrict__ bias, float* __restrict__ out)
{
    __shared__ __align__(16) bf16_t lds[2 * 32768];   // 128 KB

    const int tid = threadIdx.x;
    // r13 XCD map (FETCH 135->49 MB): 4 blocks sharing an A-panel on one XCD.
    const int x = blockIdx.x & 7;
    const int g = blockIdx.x >> 3;
    const int bm = (x * 8 + (g & 7)) * 256;
    const int bn = (g >> 3) * 256;

    const int lane = tid & 63;
    const int wid  = tid >> 6;        // 0..15
    const int wm = wid >> 2;          // 0..3 (M quarter)
    const int wn = wid & 3;           // 0..3 (N quarter)
    const int lr32 = lane & 31;       // row/col within 32x32 frag
    const int lh   = lane >> 5;       // k-half within K=16 step
    const int h7   = lr32 & 7;        // swizzle key (frag bases are 32-mult)

    // staging: wave w covers rows w*8..w*8+7 of each part; lane covers row
    // srow, source col pre-swizzled (linear LDS dest, rule 21).
    const int srow = lane >> 3;
    const int scol = ((lane & 7) ^ srow) * 8;
    const bf16_t* aS = XHb + (size_t)(bm + wid * 8 + srow) * K_GLOBAL + scol;
    const bf16_t* bS = Wb  + (size_t)(bn + wid * 8 + srow) * K_GLOBAL + scol;

    // frag-read bases (elems): parts A0,A1,B0,B1 at part*8192 within dbuf.
    // A row = wm*64 + fm*32 + lr32 -> part wm>>1, within (wm&1)*64 + ...
    const int aRd = (wm >> 1) * 8192 + ((wm & 1) * 64 + lr32) * 64;
    const int bRd = (2 + (wn >> 1)) * 8192 + ((wn & 1) * 64 + lr32) * 64;

    f32x16 acc00 = (f32x16)(0.f), acc01 = (f32x16)(0.f);
    f32x16 acc10 = (f32x16)(0.f), acc11 = (f32x16)(0.f);

    // full-tile stage: one 1KB chunk per part per wave (4 gloads/thread)
#define STAGE_FULL(T, D) {                                                    \
    _Pragma("unroll")                                                         \
    for (int p_ = 0; p_ < 4; ++p_) {                                          \
        const bf16_t* g_ = ((p_ < 2) ? aS : bS)                               \
            + (size_t)((p_ & 1) * 128) * K_GLOBAL + (T) * 64;                 \
        gload_lds16(g_, lds + (D) * 32768 + p_ * 8192 + wid * 512);           \
    }                                                                         \
}

#define BAR() { asm volatile("" ::: "memory");                                \
                __builtin_amdgcn_s_barrier();                                 \
                asm volatile("" ::: "memory"); }
#define VM0() asm volatile("s_waitcnt vmcnt(0)" ::: "memory")

    // prologue: stage T0 -> dbuf0
    STAGE_FULL(0, 0);
    VM0();
    BAR();

    for (int t = 0; t < NT; ++t) {
        const bf16_t* lb = lds + (t & 1) * 32768;

        // next tile's stage at the TOP: drained at end-of-tile VM0.
        if (t + 1 < NT) STAGE_FULL(t + 1, (t + 1) & 1);

        // fence-free compute: 4 K-steps of 16; per step 4 ds_read_b128 +
        // 4 x mfma_32x32x16 (32-cyc pipe each -> long cross-wave cover).
        __builtin_amdgcn_s_setprio(1);
#pragma unroll
        for (int ks = 0; ks < 4; ++ks) {
            const int sl = ((ks * 2 + lh) ^ h7) * 8;
            bf16x8 b0 = *(const bf16x8*)(lb + bRd + 0 * 2048 + sl);
            bf16x8 b1 = *(const bf16x8*)(lb + bRd + 1 * 2048 + sl);
            bf16x8 a0 = *(const bf16x8*)(lb + aRd + 0 * 2048 + sl);
            bf16x8 a1 = *(const bf16x8*)(lb + aRd + 1 * 2048 + sl);
            acc00 = __builtin_amdgcn_mfma_f32_32x32x16_bf16(a0, b0, acc00, 0, 0, 0);
            acc01 = __builtin_amdgcn_mfma_f32_32x32x16_bf16(a0, b1, acc01, 0, 0, 0);
            acc10 = __builtin_amdgcn_mfma_f32_32x32x16_bf16(a1, b0, acc10, 0, 0, 0);
            acc11 = __builtin_amdgcn_mfma_f32_32x32x16_bf16(a1, b1, acc11, 0, 0, 0);
        }
        __builtin_amdgcn_s_setprio(0);

        if (t + 1 < NT) { VM0(); BAR(); }
    }

#undef STAGE_FULL
#undef BAR
#undef VM0

    // ---- epilogue: bias + tanh, fp32 store.
    // 32x32 C/D layout (m74/m101): col = lane&31,
    // row = (reg&3) + 8*(reg>>2) + 4*(lane>>5).
    const float bv0 = bias[bn + wn * 64 + 0 * 32 + lr32];
    const float bv1 = bias[bn + wn * 64 + 1 * 32 + lr32];
#pragma unroll
    for (int fm = 0; fm < 2; ++fm) {
#pragma unroll
        for (int fn = 0; fn < 2; ++fn) {
            const f32x16 a = (fm == 0) ? (fn == 0 ? acc00 : acc01)
                                       : (fn == 0 ? acc10 : acc11);
            const float bv = (fn == 0) ? bv0 : bv1;
            const int col = bn + wn * 64 + fn * 32 + lr32;
#pragma unroll
            for (int r = 0; r < 16; ++r) {
                const int row = bm + wm * 64 + fm * 32
                              + (r & 3) + 8 * (r >> 2) + 4 * lh;
                out[(size_t)row * N_GLOBAL + col] = fast_tanh(a[r] + bv);
            }
        }
    }
}

// ---------------------------------------------------------------------------
// Fallback (ws too small): round-3 verified fused kernel (~169 us).
// ---------------------------------------------------------------------------
typedef float f32x4 __attribute__((ext_vector_type(4)));
#define FNT 32
__global__ __launch_bounds__(256, 2)
void rnncell_fused(const float* __restrict__ x, const float* __restrict__ h,
                   const float* __restrict__ W, const float* __restrict__ bias,
                   float* __restrict__ out)
{
    __shared__ __align__(16) bf16_t As[2][128 * 64];
    __shared__ __align__(16) bf16_t Bs[2][128 * 64];

    const int tid = threadIdx.x;
    const int bid = blockIdx.x;
    const int bm = (bid >> 3) * 128;
    const int bn = (bid & 7) * 128;

    const int lane = tid & 63;
    const int wid  = tid >> 6;
    const int wr = (wid >> 1) * 64;
    const int wc = (wid & 1) * 64;
    const int lr = lane & 15;
    const int lk = lane >> 4;

    const int row0 = tid >> 3;
    const int sl0  = tid & 7;

    f32x4 acc[4][4];
#pragma unroll
    for (int i = 0; i < 4; ++i)
#pragma unroll
        for (int j = 0; j < 4; ++j)
            acc[i][j] = (f32x4){0.f, 0.f, 0.f, 0.f};

    float4 la[4][2], lb[4][2];

#define F_LOAD_A(T) do {                                                      \
    const int k0_ = (T) * 64;                                                 \
    const float* sA_ = (k0_ < 1024)                                           \
        ? (x + (size_t)bm * IN_STRIDE + k0_)                                  \
        : (h + (size_t)bm * IN_STRIDE + (k0_ - 1024));                        \
    _Pragma("unroll")                                                         \
    for (int i_ = 0; i_ < 4; ++i_) {                                          \
        const float* pa_ = sA_ + (size_t)(row0 + i_ * 32) * IN_STRIDE + sl0 * 8; \
        la[i_][0] = *(const float4*)(pa_);                                    \
        la[i_][1] = *(const float4*)(pa_ + 4);                                \
    }                                                                         \
} while (0)

#define F_LOAD_B(T) do {                                                      \
    const float* sB_ = W + (size_t)bn * K_GLOBAL + (T) * 64;                  \
    _Pragma("unroll")                                                         \
    for (int i_ = 0; i_ < 4; ++i_) {                                          \
        const float* pb_ = sB_ + (size_t)(row0 + i_ * 32) * K_GLOBAL + sl0 * 8; \
        lb[i_][0] = *(const float4*)(pb_);                                    \
        lb[i_][1] = *(const float4*)(pb_ + 4);                                \
    }                                                                         \
} while (0)

    F_LOAD_A(0);
    F_LOAD_B(0);

    for (int t = 0; t < FNT; ++t) {
        bf16_t* __restrict__ Ab = As[t & 1];
        bf16_t* __restrict__ Bb = Bs[t & 1];

#pragma unroll
        for (int i = 0; i < 4; ++i) {
            const int row = row0 + i * 32;
            const int ssl = sl0 ^ (row & 7);
            bf16x8 va;
            va[0] = (bf16_t)la[i][0].x; va[1] = (bf16_t)la[i][0].y;
            va[2] = (bf16_t)la[i][0].z; va[3] = (bf16_t)la[i][0].w;
            va[4] = (bf16_t)la[i][1].x; va[5] = (bf16_t)la[i][1].y;
            va[6] = (bf16_t)la[i][1].z; va[7] = (bf16_t)la[i][1].w;
            *(bf16x8*)(Ab + row * 64 + ssl * 8) = va;
        }
#pragma unroll
        for (int i = 0; i < 4; ++i) {
            const int row = row0 + i * 32;
            const int ssl = sl0 ^ (row & 7);
            bf16x8 vb;
            vb[0] = (bf16_t)lb[i][0].x; vb[1] = (bf16_t)lb[i][0].y;
            vb[2] = (bf16_t)lb[i][0].z; vb[3] = (bf16_t)lb[i][0].w;
            vb[4] = (bf16_t)lb[i][1].x; vb[5] = (bf16_t)lb[i][1].y;
            vb[6] = (bf16_t)lb[i][1].z; vb[7] = (bf16_t)lb[i][1].w;
            *(bf16x8*)(Bb + row * 64 + ssl * 8) = vb;
        }

        __syncthreads();

        if (t + 1 < FNT) F_LOAD_A(t + 1);

#pragma unroll
        for (int kk = 0; kk < 2; ++kk) {
            bf16x8 af[4], bfr[4];
#pragma unroll
            for (int mf = 0; mf < 4; ++mf) {
                const int row = wr + mf * 16 + lr;
                const int sl  = (kk * 4 + lk) ^ (row & 7);
                af[mf] = *(const bf16x8*)(Ab + row * 64 + sl * 8);
            }
#pragma unroll
            for (int nf = 0; nf < 4; ++nf) {
                const int row = wc + nf * 16 + lr;
                const int sl  = (kk * 4 + lk) ^ (row & 7);
                bfr[nf] = *(const bf16x8*)(Bb + row * 64 + sl * 8);
            }
#pragma unroll
            for (int mf = 0; mf < 4; ++mf)
#pragma unroll
                for (int nf = 0; nf < 4; ++nf)
                    acc[mf][nf] = __builtin_amdgcn_mfma_f32_16x16x32_bf16(
                        af[mf], bfr[nf], acc[mf][nf], 0, 0, 0);
        }

        if (t + 1 < FNT) F_LOAD_B(t + 1);
    }
#undef F_LOAD_A
#undef F_LOAD_B

    float bv[4];
#pragma unroll
    for (int nf = 0; nf < 4; ++nf)
        bv[nf] = bias[bn + wc + nf * 16 + lr];
#pragma unroll
    for (int mf = 0; mf < 4; ++mf) {
#pragma unroll
        for (int nf = 0; nf < 4; ++nf) {
            const int col = bn + wc + nf * 16 + lr;
#pragma unroll
            for (int r = 0; r < 4; ++r) {
                const int row = bm + wr + mf * 16 + lk * 4 + r;
                out[(size_t)row * N_GLOBAL + col] = fast_tanh(acc[mf][nf][r] + bv[nf]);
            }
        }
    }
}

extern "C" void kernel_launch(void* const* d_in, const int* in_sizes, int n_in,
                              void* d_out, int out_size, void* d_ws, size_t ws_size,
                              hipStream_t stream) {
    (void)in_sizes; (void)n_in; (void)out_size;
    const float* x = (const float*)d_in[0];
    const float* h = (const float*)d_in[1];
    const float* W = (const float*)d_in[2];
    const float* b = (const float*)d_in[3];
    float* out = (float*)d_out;

    const size_t need = ((size_t)M_GLOBAL + N_GLOBAL) * K_GLOBAL * sizeof(bf16_t);
    if (ws_size >= need) {
        bf16_t* XHb = (bf16_t*)d_ws;
        bf16_t* Wb  = XHb + (size_t)M_GLOBAL * K_GLOBAL;
        cvt_pass<<<2048, 256, 0, stream>>>(x, h, W, XHb, Wb);
        gemm_w32<<<256, 1024, 0, stream>>>(XHb, Wb, b, out);
    } else {
        rnncell_fused<<<1024, 256, 0, stream>>>(x, h, W, b, out);
    }
}

// Round 20
// 85.263 us; speedup vs baseline: 1.2822x; 1.2822x over previous
//
#include <hip/hip_runtime.h>
#include <hip/hip_bf16.h>

// RNN cell: out[B,N] = tanh( concat(x,hidden)[B,K] @ W^T[K,N] + b[N] )
// M=16384, N=1024, K=2048, fp32 in/out.
// r20 = r16 GEMM (best: 73.5us, 16 waves, 16x16x32, whole-tile, 1 bar/tile)
//   with A's fp32->bf16 cvt FUSED into staging (kills the 25us XH cvt pass):
//   - A: 4x float4/thread from x/h at tile top -> regs (T14 async-split),
//     cvt + swizzled ds_write_b128 at tile END (after VM0, before barrier).
//   - B: unchanged gload_lds from a tiny W-only cvt pass (12MB, ~3us).
//   r19's 32x32 shape reverted (8.4M bank conflicts, 84.9us).

typedef __bf16 bf16_t;
typedef __bf16 bf16x8 __attribute__((ext_vector_type(8)));
typedef float  f32x4  __attribute__((ext_vector_type(4)));

#define M_GLOBAL 16384
#define N_GLOBAL 1024
#define K_GLOBAL 2048
#define IN_STRIDE 1024
#define NT 32

__device__ __forceinline__ float fast_tanh(float v) {
    float e = __expf(2.0f * v);
    return 1.0f - 2.0f * __builtin_amdgcn_rcpf(e + 1.0f);
}

// ---------------------------------------------------------------------------
// Pass 1: cvt W only. 8MB read + 4MB write -> ~2-3 us.
// ---------------------------------------------------------------------------
#define W_UNITS ((long long)N_GLOBAL * K_GLOBAL / 8)   // 262144

__global__ __launch_bounds__(256)
void cvt_w(const float* __restrict__ W, bf16_t* __restrict__ Wb)
{
    for (long long u = (long long)blockIdx.x * 256 + threadIdx.x; u < W_UNITS;
         u += (long long)gridDim.x * 256) {
        const long long e = u * 8;
        const float4 v0 = *(const float4*)(W + e);
        const float4 v1 = *(const float4*)(W + e + 4);
        bf16x8 o;
        o[0] = (bf16_t)v0.x; o[1] = (bf16_t)v0.y;
        o[2] = (bf16_t)v0.z; o[3] = (bf16_t)v0.w;
        o[4] = (bf16_t)v1.x; o[5] = (bf16_t)v1.y;
        o[6] = (bf16_t)v1.z; o[7] = (bf16_t)v1.w;
        *(bf16x8*)(Wb + e) = o;
    }
}

// ---------------------------------------------------------------------------
// Pass 2: 256x256 whole-tile GEMM, 16 waves of 64x64 (r16 geometry).
// LDS: 2 dbuf x {A0,A1,B0,B1} 128x64 halves = 128 KB (1 block/CU).
// Swizzle: LDS slot s of row r holds k-slot s^(r&7).
//   B: source-col pre-swizzled + linear gload_lds dest (rule 21, verified).
//   A: unswizzled coalesced global load -> swizzled ds_write dest.
// Race audit: A-regs/B-gloads for t+1 issued at top of t; VM0 at end of t
// drains both; A cvt+ds_write then lands in buf[(t+1)&1] whose last readers
// finished at the t-1 -> t barrier (WAR ok); lgkmcnt(0) before the raw
// barrier makes the writes visible (RAW ok).
// ---------------------------------------------------------------------------
__device__ __forceinline__ void gload_lds16(const bf16_t* g, bf16_t* l) {
    __builtin_amdgcn_global_load_lds(
        (const __attribute__((address_space(1))) void*)g,
        (__attribute__((address_space(3))) void*)l, 16, 0, 0);
}

__global__ __launch_bounds__(1024)
void gemm_fa(const float* __restrict__ x, const float* __restrict__ h,
             const bf16_t* __restrict__ Wb,
             const float* __restrict__ bias, float* __restrict__ out)
{
    __shared__ __align__(16) bf16_t lds[2 * 32768];   // 128 KB

    const int tid = threadIdx.x;
    // r13 XCD map: 4 blocks sharing an A-panel land on one XCD.
    const int xx = blockIdx.x & 7;
    const int gg = blockIdx.x >> 3;
    const int bm = (xx * 8 + (gg & 7)) * 256;
    const int bn = (gg >> 3) * 256;

    const int lane = tid & 63;
    const int wid  = tid >> 6;        // 0..15
    const int wm = wid >> 2;          // 0..3 (M quarter)
    const int wn = wid & 3;           // 0..3 (N quarter)
    const int lr = lane & 15;
    const int lk = lane >> 4;
    const int s7 = lr & 7;

    const int srow = lane >> 3;       // 0..7 (row within wave's 8-row chunk)
    const int q8   = lane & 7;        // k-slot for staging

    // A source (fp32): part p rows bm + p*128 + wid*8 + srow, cols k0 + q8*8
    const int arow0 = bm + wid * 8 + srow;
    // B source (bf16, pre-swizzled col for linear gload dest):
    const bf16_t* bS = Wb + (size_t)(bn + wid * 8 + srow) * K_GLOBAL
                          + (q8 ^ srow) * 8;

    // A LDS write dest (swizzled slot), elems:
    const int aWr = wid * 512 + srow * 64 + (q8 ^ srow) * 8;

    // frag-read bases (elems): parts A0,A1,B0,B1 at part*8192 within dbuf.
    const int aRd = (wm >> 1) * 8192 + ((wm & 1) * 64 + lr) * 64;
    const int bRd = (2 + (wn >> 1)) * 8192 + ((wn & 1) * 64 + lr) * 64;

    f32x4 acc[4][4];
#pragma unroll
    for (int i = 0; i < 4; ++i)
#pragma unroll
        for (int j = 0; j < 4; ++j)
            acc[i][j] = (f32x4){0.f, 0.f, 0.f, 0.f};

    float4 ar[2][2];   // A staged regs: [part][2x float4]

    // issue A global loads (fp32 -> regs) for tile T
#define LOAD_A(T) {                                                           \
    const int k0_ = (T) * 64;                                                 \
    const float* s_ = (k0_ < 1024) ? (x + k0_) : (h + (k0_ - 1024));          \
    _Pragma("unroll")                                                         \
    for (int p_ = 0; p_ < 2; ++p_) {                                          \
        const float* r_ = s_ + (size_t)(arow0 + p_ * 128) * IN_STRIDE + q8 * 8; \
        ar[p_][0] = *(const float4*)(r_);                                     \
        ar[p_][1] = *(const float4*)(r_ + 4);                                 \
    }                                                                         \
}

    // cvt staged A regs and write swizzled into dbuf D
#define CVT_WRITE_A(D) {                                                      \
    _Pragma("unroll")                                                         \
    for (int p_ = 0; p_ < 2; ++p_) {                                          \
        bf16x8 v_;                                                            \
        v_[0] = (bf16_t)ar[p_][0].x; v_[1] = (bf16_t)ar[p_][0].y;             \
        v_[2] = (bf16_t)ar[p_][0].z; v_[3] = (bf16_t)ar[p_][0].w;             \
        v_[4] = (bf16_t)ar[p_][1].x; v_[5] = (bf16_t)ar[p_][1].y;             \
        v_[6] = (bf16_t)ar[p_][1].z; v_[7] = (bf16_t)ar[p_][1].w;             \
        *(bf16x8*)(lds + (D) * 32768 + p_ * 8192 + aWr) = v_;                 \
    }                                                                         \
}

    // B stage via gload_lds (linear dest, pre-swizzled source)
#define STAGE_B(T, D) {                                                       \
    _Pragma("unroll")                                                         \
    for (int p_ = 2; p_ < 4; ++p_) {                                          \
        gload_lds16(bS + (size_t)((p_ & 1) * 128) * K_GLOBAL + (T) * 64,      \
                    lds + (D) * 32768 + p_ * 8192 + wid * 512);               \
    }                                                                         \
}

#define BAR() { asm volatile("" ::: "memory");                                \
                __builtin_amdgcn_s_barrier();                                 \
                asm volatile("" ::: "memory"); }
#define VM0()   asm volatile("s_waitcnt vmcnt(0)" ::: "memory")
#define LGKM0() asm volatile("s_waitcnt lgkmcnt(0)" ::: "memory")

    // prologue: stage tile 0
    LOAD_A(0);
    STAGE_B(0, 0);
    VM0();
    CVT_WRITE_A(0);
    LGKM0();
    BAR();

    for (int t = 0; t < NT; ++t) {
        const bf16_t* lb = lds + (t & 1) * 32768;

        // issue next tile's loads at the TOP (drained at end-of-tile VM0)
        if (t + 1 < NT) { LOAD_A(t + 1); STAGE_B(t + 1, (t + 1) & 1); }

        // fence-free compute: 16 ds_read_b128 + 32 MFMA per wave
        __builtin_amdgcn_s_setprio(1);
#pragma unroll
        for (int kk = 0; kk < 2; ++kk) {
            const int sl = ((kk * 4 + lk) ^ s7) * 8;
            bf16x8 bq[4];
#pragma unroll
            for (int nf = 0; nf < 4; ++nf)
                bq[nf] = *(const bf16x8*)(lb + bRd + nf * 1024 + sl);
#pragma unroll
            for (int mf = 0; mf < 4; ++mf) {
                bf16x8 af = *(const bf16x8*)(lb + aRd + mf * 1024 + sl);
#pragma unroll
                for (int nf = 0; nf < 4; ++nf)
                    acc[mf][nf] = __builtin_amdgcn_mfma_f32_16x16x32_bf16(
                        af, bq[nf], acc[mf][nf], 0, 0, 0);
            }
        }
        __builtin_amdgcn_s_setprio(0);

        if (t + 1 < NT) {
            VM0();                       // A regs + B gloads for t+1 resident
            CVT_WRITE_A((t + 1) & 1);    // A lands in the other dbuf
            LGKM0();                     // writes visible before barrier
            BAR();
        }
    }

#undef LOAD_A
#undef CVT_WRITE_A
#undef STAGE_B
#undef BAR
#undef VM0
#undef LGKM0

    // ---- epilogue: bias + tanh, fp32 store.
    // C/D layout: col = lane&15, row = (lane>>4)*4 + reg (verified r1-r18).
    float bv[4];
#pragma unroll
    for (int nf = 0; nf < 4; ++nf)
        bv[nf] = bias[bn + wn * 64 + nf * 16 + lr];
#pragma unroll
    for (int mf = 0; mf < 4; ++mf) {
#pragma unroll
        for (int nf = 0; nf < 4; ++nf) {
            const int col = bn + wn * 64 + nf * 16 + lr;
#pragma unroll
            for (int r = 0; r < 4; ++r) {
                const int row = bm + wm * 64 + mf * 16 + lk * 4 + r;
                out[(size_t)row * N_GLOBAL + col] = fast_tanh(acc[mf][nf][r] + bv[nf]);
            }
        }
    }
}

// ---------------------------------------------------------------------------
// Fallback (ws too small): round-3 verified fused kernel (~169 us).
// ---------------------------------------------------------------------------
#define FNT 32
__global__ __launch_bounds__(256, 2)
void rnncell_fused(const float* __restrict__ x, const float* __restrict__ h,
                   const float* __restrict__ W, const float* __restrict__ bias,
                   float* __restrict__ out)
{
    __shared__ __align__(16) bf16_t As[2][128 * 64];
    __shared__ __align__(16) bf16_t Bs[2][128 * 64];

    const int tid = threadIdx.x;
    const int bid = blockIdx.x;
    const int bm = (bid >> 3) * 128;
    const int bn = (bid & 7) * 128;

    const int lane = tid & 63;
    const int wid  = tid >> 6;
    const int wr = (wid >> 1) * 64;
    const int wc = (wid & 1) * 64;
    const int lr = lane & 15;
    const int lk = lane >> 4;

    const int row0 = tid >> 3;
    const int sl0  = tid & 7;

    f32x4 acc[4][4];
#pragma unroll
    for (int i = 0; i < 4; ++i)
#pragma unroll
        for (int j = 0; j < 4; ++j)
            acc[i][j] = (f32x4){0.f, 0.f, 0.f, 0.f};

    float4 la[4][2], lb[4][2];

#define F_LOAD_A(T) do {                                                      \
    const int k0_ = (T) * 64;                                                 \
    const float* sA_ = (k0_ < 1024)                                           \
        ? (x + (size_t)bm * IN_STRIDE + k0_)                                  \
        : (h + (size_t)bm * IN_STRIDE + (k0_ - 1024));                        \
    _Pragma("unroll")                                                         \
    for (int i_ = 0; i_ < 4; ++i_) {                                          \
        const float* pa_ = sA_ + (size_t)(row0 + i_ * 32) * IN_STRIDE + sl0 * 8; \
        la[i_][0] = *(const float4*)(pa_);                                    \
        la[i_][1] = *(const float4*)(pa_ + 4);                                \
    }                                                                         \
} while (0)

#define F_LOAD_B(T) do {                                                      \
    const float* sB_ = W + (size_t)bn * K_GLOBAL + (T) * 64;                  \
    _Pragma("unroll")                                                         \
    for (int i_ = 0; i_ < 4; ++i_) {                                          \
        const float* pb_ = sB_ + (size_t)(row0 + i_ * 32) * K_GLOBAL + sl0 * 8; \
        lb[i_][0] = *(const float4*)(pb_);                                    \
        lb[i_][1] = *(const float4*)(pb_ + 4);                                \
    }                                                                         \
} while (0)

    F_LOAD_A(0);
    F_LOAD_B(0);

    for (int t = 0; t < FNT; ++t) {
        bf16_t* __restrict__ Ab = As[t & 1];
        bf16_t* __restrict__ Bb = Bs[t & 1];

#pragma unroll
        for (int i = 0; i < 4; ++i) {
            const int row = row0 + i * 32;
            const int ssl = sl0 ^ (row & 7);
            bf16x8 va;
            va[0] = (bf16_t)la[i][0].x; va[1] = (bf16_t)la[i][0].y;
            va[2] = (bf16_t)la[i][0].z; va[3] = (bf16_t)la[i][0].w;
            va[4] = (bf16_t)la[i][1].x; va[5] = (bf16_t)la[i][1].y;
            va[6] = (bf16_t)la[i][1].z; va[7] = (bf16_t)la[i][1].w;
            *(bf16x8*)(Ab + row * 64 + ssl * 8) = va;
        }
#pragma unroll
        for (int i = 0; i < 4; ++i) {
            const int row = row0 + i * 32;
            const int ssl = sl0 ^ (row & 7);
            bf16x8 vb;
            vb[0] = (bf16_t)lb[i][0].x; vb[1] = (bf16_t)lb[i][0].y;
            vb[2] = (bf16_t)lb[i][0].z; vb[3] = (bf16_t)lb[i][0].w;
            vb[4] = (bf16_t)lb[i][1].x; vb[5] = (bf16_t)lb[i][1].y;
            vb[6] = (bf16_t)lb[i][1].z; vb[7] = (bf16_t)lb[i][1].w;
            *(bf16x8*)(Bb + row * 64 + ssl * 8) = vb;
        }

        __syncthreads();

        if (t + 1 < FNT) F_LOAD_A(t + 1);

#pragma unroll
        for (int kk = 0; kk < 2; ++kk) {
            bf16x8 af[4], bfr[4];
#pragma unroll
            for (int mf = 0; mf < 4; ++mf) {
                const int row = wr + mf * 16 + lr;
                const int sl  = (kk * 4 + lk) ^ (row & 7);
                af[mf] = *(const bf16x8*)(Ab + row * 64 + sl * 8);
            }
#pragma unroll
            for (int nf = 0; nf < 4; ++nf) {
                const int row = wc + nf * 16 + lr;
                const int sl  = (kk * 4 + lk) ^ (row & 7);
                bfr[nf] = *(const bf16x8*)(Bb + row * 64 + sl * 8);
            }
#pragma unroll
            for (int mf = 0; mf < 4; ++mf)
#pragma unroll
                for (int nf = 0; nf < 4; ++nf)
                    acc[mf][nf] = __builtin_amdgcn_mfma_f32_16x16x32_bf16(
                        af[mf], bfr[nf], acc[mf][nf], 0, 0, 0);
        }

        if (t + 1 < FNT) F_LOAD_B(t + 1);
    }
#undef F_LOAD_A
#undef F_LOAD_B

    float bv[4];
#pragma unroll
    for (int nf = 0; nf < 4; ++nf)
        bv[nf] = bias[bn + wc + nf * 16 + lr];
#pragma unroll
    for (int mf = 0; mf < 4; ++mf) {
#pragma unroll
        for (int nf = 0; nf < 4; ++nf) {
            const int col = bn + wc + nf * 16 + lr;
#pragma unroll
            for (int r = 0; r < 4; ++r) {
                const int row = bm + wr + mf * 16 + lk * 4 + r;
                out[(size_t)row * N_GLOBAL + col] = fast_tanh(acc[mf][nf][r] + bv[nf]);
            }
        }
    }
}

extern "C" void kernel_launch(void* const* d_in, const int* in_sizes, int n_in,
                              void* d_out, int out_size, void* d_ws, size_t ws_size,
                              hipStream_t stream) {
    (void)in_sizes; (void)n_in; (void)out_size;
    const float* x = (const float*)d_in[0];
    const float* h = (const float*)d_in[1];
    const float* W = (const float*)d_in[2];
    const float* b = (const float*)d_in[3];
    float* out = (float*)d_out;

    const size_t need = (size_t)N_GLOBAL * K_GLOBAL * sizeof(bf16_t);  // 4 MB
    if (ws_size >= need) {
        bf16_t* Wb = (bf16_t*)d_ws;
        cvt_w<<<512, 256, 0, stream>>>(W, Wb);
        gemm_fa<<<256, 1024, 0, stream>>>(x, h, Wb, b, out);
    } else {
        rnncell_fused<<<1024, 256, 0, stream>>>(x, h, W, b, out);
    }
}